// Round 2
// baseline (485.012 us; speedup 1.0000x reference)
//
#include <hip/hip_runtime.h>
#include <hip/hip_bf16.h>
#include <math.h>

#define N_TOK 4096
#define D_IN  768
#define N_EXP 8
#define H_DIM 3072
#define NP    8192      // N_TOK * TOPK
#define BM    128
#define BK    64
#define BN1   128
#define BN2   128
#define MAXT  72        // NP/BM + N_EXP

typedef float f32x4 __attribute__((ext_vector_type(4)));
typedef short s16x8 __attribute__((ext_vector_type(8)));

__device__ __forceinline__ unsigned short f2bf(float f) {
    unsigned int u = __builtin_bit_cast(unsigned int, f);
    u += 0x7fffu + ((u >> 16) & 1u);
    return (unsigned short)(u >> 16);
}

__device__ __forceinline__ void gload_lds16(const void* g, void* l) {
    __builtin_amdgcn_global_load_lds(
        (const __attribute__((address_space(1))) unsigned int*)g,
        (__attribute__((address_space(3))) unsigned int*)l, 16, 0, 0);
}

// ---- transpose + f32->bf16 convert: src[e][R][C] -> dst[e][C][R] ----
__global__ __launch_bounds__(256) void transpose_cvt_kernel(
    const float* __restrict__ src, unsigned short* __restrict__ dst, int R, int C) {
    __shared__ float t[32][33];
    int e = blockIdx.z;
    int c0 = blockIdx.x * 32, r0 = blockIdx.y * 32;
    int tx = threadIdx.x, ty = threadIdx.y; // 32 x 8
    const float* s = src + (size_t)e * R * C;
    unsigned short* d = dst + (size_t)e * R * C;
#pragma unroll
    for (int i = 0; i < 4; i++)
        t[ty + 8 * i][tx] = s[(size_t)(r0 + ty + 8 * i) * C + c0 + tx];
    __syncthreads();
#pragma unroll
    for (int i = 0; i < 4; i++)
        d[(size_t)(c0 + ty + 8 * i) * R + r0 + tx] = f2bf(t[tx][ty + 8 * i]);
}

// ---- router: logits, softmax, top2, per-expert stats ----
__global__ __launch_bounds__(64) void router_kernel(
    const float* __restrict__ x, const float* __restrict__ rw, const float* __restrict__ rb,
    int* counts, int* top1cnt, float* probs_sum, int* tk_e, float* tk_w) {
    __shared__ __align__(16) float s_rw[D_IN * N_EXP];
    __shared__ float s_ps[N_EXP];
    __shared__ int s_cnt[N_EXP], s_t1[N_EXP];
    int tid = threadIdx.x;
    for (int i = tid; i < D_IN * N_EXP / 4; i += 64)
        ((float4*)s_rw)[i] = ((const float4*)rw)[i];
    if (tid < N_EXP) { s_ps[tid] = 0.f; s_cnt[tid] = 0; s_t1[tid] = 0; }
    __syncthreads();

    int tok = blockIdx.x * 64 + tid;
    float acc[N_EXP];
#pragma unroll
    for (int e = 0; e < N_EXP; e++) acc[e] = rb[e];
    const float* xr = x + (size_t)tok * D_IN;
    for (int d = 0; d < D_IN; d++) {
        float xv = xr[d];
#pragma unroll
        for (int e = 0; e < N_EXP; e++) acc[e] += xv * s_rw[d * N_EXP + e];
    }
    float m = acc[0];
#pragma unroll
    for (int e = 1; e < N_EXP; e++) m = fmaxf(m, acc[e]);
    float p[N_EXP], s = 0.f;
#pragma unroll
    for (int e = 0; e < N_EXP; e++) { p[e] = __expf(acc[e] - m); s += p[e]; }
    float inv = 1.f / s;
#pragma unroll
    for (int e = 0; e < N_EXP; e++) p[e] *= inv;
    int e0 = 0;
#pragma unroll
    for (int e = 1; e < N_EXP; e++) if (p[e] > p[e0]) e0 = e;
    int e1 = (e0 == 0) ? 1 : 0;
#pragma unroll
    for (int e = 0; e < N_EXP; e++) if (e != e0 && p[e] > p[e1]) e1 = e;
    float denom = 1.f / (p[e0] + p[e1]);
    tk_e[tok * 2] = e0; tk_e[tok * 2 + 1] = e1;
    tk_w[tok * 2] = p[e0] * denom; tk_w[tok * 2 + 1] = p[e1] * denom;
    atomicAdd(&s_cnt[e0], 1); atomicAdd(&s_cnt[e1], 1); atomicAdd(&s_t1[e0], 1);
#pragma unroll
    for (int e = 0; e < N_EXP; e++) atomicAdd(&s_ps[e], p[e]);
    __syncthreads();
    if (tid < N_EXP) {
        atomicAdd(&counts[tid], s_cnt[tid]);
        atomicAdd(&top1cnt[tid], s_t1[tid]);
        atomicAdd(&probs_sum[tid], s_ps[tid]);
    }
}

// ---- scan: segment offsets, tile table, aux loss ----
__global__ void scan_kernel(const int* counts, const int* top1cnt, const float* probs_sum,
                            int* segOff, int* cursors, int* tileE, int* tileB, int* nTiles,
                            float* aux_out) {
    if (threadIdx.x == 0 && blockIdx.x == 0) {
        int off = 0, nt = 0;
        for (int e = 0; e < N_EXP; e++) {
            segOff[e] = off; cursors[e] = off;
            int c = counts[e]; off += c;
            int t = (c + BM - 1) / BM;
            for (int i = 0; i < t; i++) { tileE[nt] = e; tileB[nt] = i * BM; nt++; }
        }
        segOff[N_EXP] = off;
        for (int i = nt; i < MAXT; i++) { tileE[i] = -1; tileB[i] = 0; }
        *nTiles = nt;
        float aux = 0.f;
        for (int e = 0; e < N_EXP; e++) aux += (float)top1cnt[e] * probs_sum[e];
        aux_out[0] = (float)N_EXP * aux / ((float)N_TOK * (float)N_TOK);
    }
}

// ---- scatter: build permutation ----
__global__ __launch_bounds__(64) void scatter_kernel(
    const int* __restrict__ tk_e, const float* __restrict__ tk_w,
    int* cursors, int* rowTok, float* rowGate, int* pairPos) {
    int tok = blockIdx.x * 64 + threadIdx.x;
#pragma unroll
    for (int k = 0; k < 2; k++) {
        int e = tk_e[tok * 2 + k];
        int pos = atomicAdd(&cursors[e], 1);
        rowTok[pos] = tok;
        rowGate[pos] = tk_w[tok * 2 + k];
        pairPos[tok * 2 + k] = pos;
    }
}

// ---- gather x rows -> bf16 Xg ----
__global__ __launch_bounds__(192) void gather_kernel(
    const float* __restrict__ x, const int* __restrict__ rowTok, unsigned short* __restrict__ Xg) {
    int pos = blockIdx.x;
    int t = rowTok[pos];
    int i = threadIdx.x; // 0..191
    float4 v = ((const float4*)(x + (size_t)t * D_IN))[i];
    unsigned long long pk = (unsigned long long)f2bf(v.x)
                          | ((unsigned long long)f2bf(v.y) << 16)
                          | ((unsigned long long)f2bf(v.z) << 32)
                          | ((unsigned long long)f2bf(v.w) << 48);
    *(unsigned long long*)(Xg + (size_t)pos * D_IN + (size_t)i * 4) = pk;
}

// ---- ffn1: H = silu(X@W1+b1) * (X@W2+b2), bf16 out. BM=128 BN1=128 BK=64 ----
__global__ __launch_bounds__(256) void ffn1_kernel(
    const unsigned short* __restrict__ Xg, const unsigned short* __restrict__ W1T,
    const unsigned short* __restrict__ W2T, const float* __restrict__ b1,
    const float* __restrict__ b2, unsigned short* __restrict__ Hbuf,
    const int* __restrict__ tileE, const int* __restrict__ tileB,
    const int* __restrict__ segOff, const int* __restrict__ counts) {
    int bx = blockIdx.x;
    int e = tileE[bx];
    if (e < 0) return;
    int lb = tileB[bx];
    int g0 = segOff[e] + lb;
    int vr = counts[e] - lb; if (vr > BM) vr = BM;
    int n0 = blockIdx.y * BN1;

    __shared__ __align__(16) unsigned short sA[BM * BK];
    __shared__ __align__(16) unsigned short sB1[BN1 * BK];
    __shared__ __align__(16) unsigned short sB2[BN1 * BK];

    int tid = threadIdx.x, lane = tid & 63, w = tid >> 6;
    int wm = w >> 1, wn = w & 1;
    int lr = lane & 15, lh = lane >> 4;

    f32x4 acc1[4][4], acc2[4][4];
#pragma unroll
    for (int a = 0; a < 4; a++)
#pragma unroll
        for (int b = 0; b < 4; b++) { acc1[a][b] = (f32x4)0.f; acc2[a][b] = (f32x4)0.f; }

    const unsigned short* W1e = W1T + (size_t)e * H_DIM * D_IN;
    const unsigned short* W2e = W2T + (size_t)e * H_DIM * D_IN;

    for (int kt = 0; kt < D_IN / BK; ++kt) {
        int kb = kt * BK;
#pragma unroll
        for (int ra = 0; ra < 4; ra++) {
            int o = ra * 4096 + tid * 16;
            int row = o >> 7;
            int c = ((o >> 4) & 7) ^ (row & 7);
            int gr = g0 + row; if (gr > NP - 1) gr = NP - 1;
            gload_lds16(Xg + (size_t)gr * D_IN + kb + c * 8, (char*)sA + o);
        }
#pragma unroll
        for (int rb2 = 0; rb2 < 4; rb2++) {
            int o = rb2 * 4096 + tid * 16;
            int row = o >> 7;
            int c = ((o >> 4) & 7) ^ (row & 7);
            size_t src = (size_t)(n0 + row) * D_IN + kb + c * 8;
            gload_lds16(W1e + src, (char*)sB1 + o);
            gload_lds16(W2e + src, (char*)sB2 + o);
        }
        asm volatile("s_waitcnt vmcnt(0)" ::: "memory");
        __syncthreads();
#pragma unroll
        for (int ks = 0; ks < 2; ++ks) {
            int sb = ks * 4 + lh;
            s16x8 av[4];
#pragma unroll
            for (int mf = 0; mf < 4; ++mf) {
                int r = wm * 64 + mf * 16 + lr;
                av[mf] = *(const s16x8*)&sA[r * 64 + ((sb ^ (r & 7)) << 3)];
            }
#pragma unroll
            for (int nf = 0; nf < 4; ++nf) {
                int n = wn * 64 + nf * 16 + lr;
                int off = n * 64 + ((sb ^ (n & 7)) << 3);
                s16x8 bv1 = *(const s16x8*)&sB1[off];
                s16x8 bv2 = *(const s16x8*)&sB2[off];
#pragma unroll
                for (int mf = 0; mf < 4; ++mf) {
                    acc1[mf][nf] = __builtin_amdgcn_mfma_f32_16x16x32_bf16(av[mf], bv1, acc1[mf][nf], 0, 0, 0);
                    acc2[mf][nf] = __builtin_amdgcn_mfma_f32_16x16x32_bf16(av[mf], bv2, acc2[mf][nf], 0, 0, 0);
                }
            }
        }
        __syncthreads();
    }
#pragma unroll
    for (int mf = 0; mf < 4; ++mf) {
        int rbase = wm * 64 + mf * 16 + lh * 4;
#pragma unroll
        for (int nf = 0; nf < 4; ++nf) {
            int n = n0 + wn * 64 + nf * 16 + lr;
            float bb1 = b1[e * H_DIM + n], bb2 = b2[e * H_DIM + n];
#pragma unroll
            for (int j = 0; j < 4; ++j) {
                int r = rbase + j;
                if (r < vr) {
                    float x1 = acc1[mf][nf][j] + bb1;
                    float x2 = acc2[mf][nf][j] + bb2;
                    float h = x1 / (1.f + __expf(-x1)) * x2;
                    Hbuf[(size_t)(g0 + r) * H_DIM + n] = f2bf(h);
                }
            }
        }
    }
}

// ---- ffn2: Y = gate * (H@W3 + b3), f32 out. BM=128 BN2=128 BK=64, dbuf prefetch ----
__global__ __launch_bounds__(256) void ffn2_kernel(
    const unsigned short* __restrict__ Hbuf, const unsigned short* __restrict__ W3T,
    const float* __restrict__ b3, const float* __restrict__ rowGate,
    float* __restrict__ Ybuf,
    const int* __restrict__ tileE, const int* __restrict__ tileB,
    const int* __restrict__ segOff, const int* __restrict__ counts) {
    int bx = blockIdx.x;
    int e = tileE[bx];
    if (e < 0) return;
    int lb = tileB[bx];
    int g0 = segOff[e] + lb;
    int vr = counts[e] - lb; if (vr > BM) vr = BM;
    int n0 = blockIdx.y * BN2;

    __shared__ __align__(16) unsigned short sA[2][BM * BK];
    __shared__ __align__(16) unsigned short sB[2][BN2 * BK];

    int tid = threadIdx.x, lane = tid & 63, w = tid >> 6;
    int wm = w >> 1, wn = w & 1;
    int lr = lane & 15, lh = lane >> 4;

    f32x4 acc[4][4];
#pragma unroll
    for (int a = 0; a < 4; a++)
#pragma unroll
        for (int b = 0; b < 4; b++) acc[a][b] = (f32x4)0.f;

    const unsigned short* W3e = W3T + (size_t)e * D_IN * H_DIM;

    auto stage = [&](int buf, int kt) {
        int kb = kt * BK;
#pragma unroll
        for (int ra = 0; ra < 4; ra++) {
            int o = ra * 4096 + tid * 16;
            int row = o >> 7;
            int c = ((o >> 4) & 7) ^ (row & 7);
            int gr = g0 + row; if (gr > NP - 1) gr = NP - 1;
            gload_lds16(Hbuf + (size_t)gr * H_DIM + kb + c * 8, (char*)&sA[buf][0] + o);
        }
#pragma unroll
        for (int rb2 = 0; rb2 < 4; rb2++) {
            int o = rb2 * 4096 + tid * 16;
            int row = o >> 7;
            int c = ((o >> 4) & 7) ^ (row & 7);
            gload_lds16(W3e + (size_t)(n0 + row) * H_DIM + kb + c * 8, (char*)&sB[buf][0] + o);
        }
    };

    const int NKT = H_DIM / BK;
    stage(0, 0);
    asm volatile("s_waitcnt vmcnt(0)" ::: "memory");
    __syncthreads();
    int cur = 0;
    for (int kt = 0; kt < NKT; ++kt) {
        if (kt + 1 < NKT) stage(cur ^ 1, kt + 1);
#pragma unroll
        for (int ks = 0; ks < 2; ++ks) {
            int sb = ks * 4 + lh;
            s16x8 av[4];
#pragma unroll
            for (int mf = 0; mf < 4; ++mf) {
                int r = wm * 64 + mf * 16 + lr;
                av[mf] = *(const s16x8*)&sA[cur][r * 64 + ((sb ^ (r & 7)) << 3)];
            }
#pragma unroll
            for (int nf = 0; nf < 4; ++nf) {
                int n = wn * 64 + nf * 16 + lr;
                s16x8 bv = *(const s16x8*)&sB[cur][n * 64 + ((sb ^ (n & 7)) << 3)];
#pragma unroll
                for (int mf = 0; mf < 4; ++mf)
                    acc[mf][nf] = __builtin_amdgcn_mfma_f32_16x16x32_bf16(av[mf], bv, acc[mf][nf], 0, 0, 0);
            }
        }
        asm volatile("s_waitcnt vmcnt(0)" ::: "memory");
        __syncthreads();
        cur ^= 1;
    }
#pragma unroll
    for (int mf = 0; mf < 4; ++mf) {
        int rbase = wm * 64 + mf * 16 + lh * 4;
#pragma unroll
        for (int nf = 0; nf < 4; ++nf) {
            int n = n0 + wn * 64 + nf * 16 + lr;
            float bb = b3[e * D_IN + n];
#pragma unroll
            for (int j = 0; j < 4; ++j) {
                int r = rbase + j;
                if (r < vr) {
                    float g = rowGate[g0 + r];
                    Ybuf[(size_t)(g0 + r) * D_IN + n] = g * (acc[mf][nf][j] + bb);
                }
            }
        }
    }
}

// ---- combine: out[t] = Y[p0[t]] + Y[p1[t]] ----
__global__ __launch_bounds__(192) void combine_kernel(
    const float* __restrict__ Ybuf, const int* __restrict__ pairPos, float* __restrict__ out) {
    int t = blockIdx.x, i = threadIdx.x;
    int p0 = pairPos[t * 2], p1 = pairPos[t * 2 + 1];
    float4 a = ((const float4*)(Ybuf + (size_t)p0 * D_IN))[i];
    float4 b = ((const float4*)(Ybuf + (size_t)p1 * D_IN))[i];
    float4 r; r.x = a.x + b.x; r.y = a.y + b.y; r.z = a.z + b.z; r.w = a.w + b.w;
    ((float4*)(out + (size_t)t * D_IN))[i] = r;
}

extern "C" void kernel_launch(void* const* d_in, const int* in_sizes, int n_in,
                              void* d_out, int out_size, void* d_ws, size_t ws_size,
                              hipStream_t stream) {
    const float* x  = (const float*)d_in[0];
    const float* rw = (const float*)d_in[1];
    const float* rb = (const float*)d_in[2];
    const float* w1 = (const float*)d_in[3];
    const float* b1 = (const float*)d_in[4];
    const float* w2 = (const float*)d_in[5];
    const float* b2 = (const float*)d_in[6];
    const float* w3 = (const float*)d_in[7];
    const float* b3 = (const float*)d_in[8];
    float* out = (float*)d_out;

    char* ws = (char*)d_ws;
    const size_t sW = (size_t)N_EXP * H_DIM * D_IN * 2;
    unsigned short* W1T = (unsigned short*)(ws);
    unsigned short* W2T = (unsigned short*)(ws + sW);
    unsigned short* W3T = (unsigned short*)(ws + 2 * sW);
    unsigned short* Xg  = (unsigned short*)(ws + 3 * sW);
    unsigned short* Hb  = (unsigned short*)(ws + 3 * sW + (size_t)NP * D_IN * 2);
    float* Yb = (float*)(ws + 3 * sW + (size_t)NP * D_IN * 2 + (size_t)NP * H_DIM * 2);
    char* meta = (char*)(Yb + (size_t)NP * D_IN);
    int*   counts  = (int*)(meta + 0);
    int*   top1    = (int*)(meta + 32);
    float* psum    = (float*)(meta + 64);
    int*   cursors = (int*)(meta + 96);
    int*   segOff  = (int*)(meta + 128);
    int*   nTiles  = (int*)(meta + 176);
    int*   tileE   = (int*)(meta + 192);
    int*   tileB   = (int*)(meta + 512);
    int*   tk_e    = (int*)(meta + 1024);
    float* tk_w    = (float*)(meta + 1024 + 32768);
    int*   rowTok  = (int*)(meta + 1024 + 65536);
    float* rowGate = (float*)(meta + 1024 + 98304);
    int*   pairPos = (int*)(meta + 1024 + 131072);
    size_t need = (size_t)(meta - ws) + 1024 + 131072 + 32768;
    if (ws_size < need) return;

    hipMemsetAsync(meta, 0, 96, stream);
    dim3 tb(32, 8);
    transpose_cvt_kernel<<<dim3(H_DIM / 32, D_IN / 32, N_EXP), tb, 0, stream>>>(w1, W1T, D_IN, H_DIM);
    transpose_cvt_kernel<<<dim3(H_DIM / 32, D_IN / 32, N_EXP), tb, 0, stream>>>(w2, W2T, D_IN, H_DIM);
    transpose_cvt_kernel<<<dim3(D_IN / 32, H_DIM / 32, N_EXP), tb, 0, stream>>>(w3, W3T, H_DIM, D_IN);
    router_kernel<<<N_TOK / 64, 64, 0, stream>>>(x, rw, rb, counts, top1, psum, tk_e, tk_w);
    scan_kernel<<<1, 64, 0, stream>>>(counts, top1, psum, segOff, cursors, tileE, tileB, nTiles,
                                      out + (size_t)N_TOK * D_IN);
    scatter_kernel<<<N_TOK / 64, 64, 0, stream>>>(tk_e, tk_w, cursors, rowTok, rowGate, pairPos);
    gather_kernel<<<NP, 192, 0, stream>>>(x, rowTok, Xg);
    ffn1_kernel<<<dim3(MAXT, H_DIM / BN1), 256, 0, stream>>>(Xg, W1T, W2T, b1, b2, Hb,
                                                             tileE, tileB, segOff, counts);
    ffn2_kernel<<<dim3(MAXT, D_IN / BN2), 256, 0, stream>>>(Hb, W3T, b3, rowGate, Yb,
                                                            tileE, tileB, segOff, counts);
    combine_kernel<<<N_TOK, 192, 0, stream>>>(Yb, pairPos, out);
}

// Round 3
// 386.751 us; speedup vs baseline: 1.2541x; 1.2541x over previous
//
#include <hip/hip_runtime.h>
#include <hip/hip_bf16.h>
#include <math.h>

#define N_TOK 4096
#define D_IN  768
#define N_EXP 8
#define H_DIM 3072
#define NP    8192      // N_TOK * TOPK
#define BM    128
#define BK    64
#define BN1   64
#define BN2   128
#define MAXT  72        // NP/BM + N_EXP

typedef float f32x4 __attribute__((ext_vector_type(4)));
typedef short s16x8 __attribute__((ext_vector_type(8)));

__device__ __forceinline__ unsigned short f2bf(float f) {
    unsigned int u = __builtin_bit_cast(unsigned int, f);
    u += 0x7fffu + ((u >> 16) & 1u);
    return (unsigned short)(u >> 16);
}

__device__ __forceinline__ void gload_lds16(const void* g, void* l) {
    __builtin_amdgcn_global_load_lds(
        (const __attribute__((address_space(1))) unsigned int*)g,
        (__attribute__((address_space(3))) unsigned int*)l, 16, 0, 0);
}

// ---- transpose + f32->bf16 convert: src[e][R][C] -> dst[e][C][R] ----
__global__ __launch_bounds__(256) void transpose_cvt_kernel(
    const float* __restrict__ src, unsigned short* __restrict__ dst, int R, int C) {
    __shared__ float t[32][33];
    int e = blockIdx.z;
    int c0 = blockIdx.x * 32, r0 = blockIdx.y * 32;
    int tx = threadIdx.x, ty = threadIdx.y; // 32 x 8
    const float* s = src + (size_t)e * R * C;
    unsigned short* d = dst + (size_t)e * R * C;
#pragma unroll
    for (int i = 0; i < 4; i++)
        t[ty + 8 * i][tx] = s[(size_t)(r0 + ty + 8 * i) * C + c0 + tx];
    __syncthreads();
#pragma unroll
    for (int i = 0; i < 4; i++)
        d[(size_t)(c0 + ty + 8 * i) * R + r0 + tx] = f2bf(t[tx][ty + 8 * i]);
}

// ---- router: logits, softmax, top2, per-expert stats ----
__global__ __launch_bounds__(64) void router_kernel(
    const float* __restrict__ x, const float* __restrict__ rw, const float* __restrict__ rb,
    int* counts, int* top1cnt, float* probs_sum, int* tk_e, float* tk_w) {
    __shared__ __align__(16) float s_rw[D_IN * N_EXP];
    __shared__ float s_ps[N_EXP];
    __shared__ int s_cnt[N_EXP], s_t1[N_EXP];
    int tid = threadIdx.x;
    for (int i = tid; i < D_IN * N_EXP / 4; i += 64)
        ((float4*)s_rw)[i] = ((const float4*)rw)[i];
    if (tid < N_EXP) { s_ps[tid] = 0.f; s_cnt[tid] = 0; s_t1[tid] = 0; }
    __syncthreads();

    int tok = blockIdx.x * 64 + tid;
    float acc[N_EXP];
#pragma unroll
    for (int e = 0; e < N_EXP; e++) acc[e] = rb[e];
    const float* xr = x + (size_t)tok * D_IN;
    for (int d = 0; d < D_IN; d++) {
        float xv = xr[d];
#pragma unroll
        for (int e = 0; e < N_EXP; e++) acc[e] += xv * s_rw[d * N_EXP + e];
    }
    float m = acc[0];
#pragma unroll
    for (int e = 1; e < N_EXP; e++) m = fmaxf(m, acc[e]);
    float p[N_EXP], s = 0.f;
#pragma unroll
    for (int e = 0; e < N_EXP; e++) { p[e] = __expf(acc[e] - m); s += p[e]; }
    float inv = 1.f / s;
#pragma unroll
    for (int e = 0; e < N_EXP; e++) p[e] *= inv;
    int e0 = 0;
#pragma unroll
    for (int e = 1; e < N_EXP; e++) if (p[e] > p[e0]) e0 = e;
    int e1 = (e0 == 0) ? 1 : 0;
#pragma unroll
    for (int e = 0; e < N_EXP; e++) if (e != e0 && p[e] > p[e1]) e1 = e;
    float denom = 1.f / (p[e0] + p[e1]);
    tk_e[tok * 2] = e0; tk_e[tok * 2 + 1] = e1;
    tk_w[tok * 2] = p[e0] * denom; tk_w[tok * 2 + 1] = p[e1] * denom;
    atomicAdd(&s_cnt[e0], 1); atomicAdd(&s_cnt[e1], 1); atomicAdd(&s_t1[e0], 1);
#pragma unroll
    for (int e = 0; e < N_EXP; e++) atomicAdd(&s_ps[e], p[e]);
    __syncthreads();
    if (tid < N_EXP) {
        atomicAdd(&counts[tid], s_cnt[tid]);
        atomicAdd(&top1cnt[tid], s_t1[tid]);
        atomicAdd(&probs_sum[tid], s_ps[tid]);
    }
}

// ---- scan: segment offsets, tile table, aux loss ----
__global__ void scan_kernel(const int* counts, const int* top1cnt, const float* probs_sum,
                            int* segOff, int* cursors, int* tileE, int* tileB, int* nTiles,
                            float* aux_out) {
    if (threadIdx.x == 0 && blockIdx.x == 0) {
        int off = 0, nt = 0;
        for (int e = 0; e < N_EXP; e++) {
            segOff[e] = off; cursors[e] = off;
            int c = counts[e]; off += c;
            int t = (c + BM - 1) / BM;
            for (int i = 0; i < t; i++) { tileE[nt] = e; tileB[nt] = i * BM; nt++; }
        }
        segOff[N_EXP] = off;
        for (int i = nt; i < MAXT; i++) { tileE[i] = -1; tileB[i] = 0; }
        *nTiles = nt;
        float aux = 0.f;
        for (int e = 0; e < N_EXP; e++) aux += (float)top1cnt[e] * probs_sum[e];
        aux_out[0] = (float)N_EXP * aux / ((float)N_TOK * (float)N_TOK);
    }
}

// ---- scatter: build permutation ----
__global__ __launch_bounds__(64) void scatter_kernel(
    const int* __restrict__ tk_e, const float* __restrict__ tk_w,
    int* cursors, int* rowTok, float* rowGate, int* pairPos) {
    int tok = blockIdx.x * 64 + threadIdx.x;
#pragma unroll
    for (int k = 0; k < 2; k++) {
        int e = tk_e[tok * 2 + k];
        int pos = atomicAdd(&cursors[e], 1);
        rowTok[pos] = tok;
        rowGate[pos] = tk_w[tok * 2 + k];
        pairPos[tok * 2 + k] = pos;
    }
}

// ---- gather x rows -> bf16 Xg ----
__global__ __launch_bounds__(192) void gather_kernel(
    const float* __restrict__ x, const int* __restrict__ rowTok, unsigned short* __restrict__ Xg) {
    int pos = blockIdx.x;
    int t = rowTok[pos];
    int i = threadIdx.x; // 0..191
    float4 v = ((const float4*)(x + (size_t)t * D_IN))[i];
    unsigned long long pk = (unsigned long long)f2bf(v.x)
                          | ((unsigned long long)f2bf(v.y) << 16)
                          | ((unsigned long long)f2bf(v.z) << 32)
                          | ((unsigned long long)f2bf(v.w) << 48);
    *(unsigned long long*)(Xg + (size_t)pos * D_IN + (size_t)i * 4) = pk;
}

// ---- ffn1: H = silu(X@W1+b1) * (X@W2+b2), bf16 out ----
// BM=128 BN1=64 BK=64, 256 thr, counted-vmcnt double-buffer (8 loads/thread/iter)
__global__ __launch_bounds__(256) void ffn1_kernel(
    const unsigned short* __restrict__ Xg, const unsigned short* __restrict__ W1T,
    const unsigned short* __restrict__ W2T, const float* __restrict__ b1,
    const float* __restrict__ b2, unsigned short* __restrict__ Hbuf,
    const int* __restrict__ tileE, const int* __restrict__ tileB,
    const int* __restrict__ segOff, const int* __restrict__ counts) {
    int bx = blockIdx.x;
    int e = tileE[bx];
    if (e < 0) return;
    int lb = tileB[bx];
    int g0 = segOff[e] + lb;
    int vr = counts[e] - lb; if (vr > BM) vr = BM;
    int n0 = blockIdx.y * BN1;

    __shared__ __align__(16) unsigned short sA[2][BM * BK];   // 32 KB
    __shared__ __align__(16) unsigned short sB1[2][BN1 * BK]; // 16 KB
    __shared__ __align__(16) unsigned short sB2[2][BN1 * BK]; // 16 KB

    int tid = threadIdx.x, lane = tid & 63, w = tid >> 6;
    int wm = w >> 1, wn = w & 1;
    int lr = lane & 15, lh = lane >> 4;

    f32x4 acc1[4][2], acc2[4][2];
#pragma unroll
    for (int a = 0; a < 4; a++)
#pragma unroll
        for (int b = 0; b < 2; b++) { acc1[a][b] = (f32x4)0.f; acc2[a][b] = (f32x4)0.f; }

    const unsigned short* W1e = W1T + (size_t)e * H_DIM * D_IN;
    const unsigned short* W2e = W2T + (size_t)e * H_DIM * D_IN;

    auto stage = [&](int buf, int kt) {
        int kb = kt * BK;
#pragma unroll
        for (int ra = 0; ra < 4; ra++) {
            int o = ra * 4096 + tid * 16;
            int row = o >> 7;
            int c = ((o >> 4) & 7) ^ (row & 7);
            int gr = g0 + row; if (gr > NP - 1) gr = NP - 1;
            gload_lds16(Xg + (size_t)gr * D_IN + kb + c * 8, (char*)&sA[buf][0] + o);
        }
#pragma unroll
        for (int rb2 = 0; rb2 < 2; rb2++) {
            int o = rb2 * 4096 + tid * 16;
            int row = o >> 7;
            int c = ((o >> 4) & 7) ^ (row & 7);
            size_t src = (size_t)(n0 + row) * D_IN + kb + c * 8;
            gload_lds16(W1e + src, (char*)&sB1[buf][0] + o);
            gload_lds16(W2e + src, (char*)&sB2[buf][0] + o);
        }
    };

    const int NKT = D_IN / BK; // 12
    stage(0, 0);
    stage(1, 1);
    __builtin_amdgcn_sched_barrier(0);
    for (int kt = 0; kt < NKT; ++kt) {
        // wait for tile kt only; tile kt+1's 8 loads stay in flight
        if (kt < NKT - 1) { asm volatile("s_waitcnt vmcnt(8)" ::: "memory"); }
        else              { asm volatile("s_waitcnt vmcnt(0)" ::: "memory"); }
        __builtin_amdgcn_s_barrier();
        __builtin_amdgcn_sched_barrier(0);
        int cur = kt & 1;
#pragma unroll
        for (int ks = 0; ks < 2; ++ks) {
            int sb = ks * 4 + lh;
            s16x8 av[4];
#pragma unroll
            for (int mf = 0; mf < 4; ++mf) {
                int r = wm * 64 + mf * 16 + lr;
                av[mf] = *(const s16x8*)&sA[cur][r * 64 + ((sb ^ (r & 7)) << 3)];
            }
#pragma unroll
            for (int nf = 0; nf < 2; ++nf) {
                int n = wn * 32 + nf * 16 + lr;
                int off = n * 64 + ((sb ^ (n & 7)) << 3);
                s16x8 bv1 = *(const s16x8*)&sB1[cur][off];
                s16x8 bv2 = *(const s16x8*)&sB2[cur][off];
#pragma unroll
                for (int mf = 0; mf < 4; ++mf) {
                    acc1[mf][nf] = __builtin_amdgcn_mfma_f32_16x16x32_bf16(av[mf], bv1, acc1[mf][nf], 0, 0, 0);
                    acc2[mf][nf] = __builtin_amdgcn_mfma_f32_16x16x32_bf16(av[mf], bv2, acc2[mf][nf], 0, 0, 0);
                }
            }
        }
        __builtin_amdgcn_sched_barrier(0);
        __builtin_amdgcn_s_barrier();
        if (kt + 2 < NKT) { stage(cur, kt + 2); __builtin_amdgcn_sched_barrier(0); }
    }
#pragma unroll
    for (int mf = 0; mf < 4; ++mf) {
        int rbase = wm * 64 + mf * 16 + lh * 4;
#pragma unroll
        for (int nf = 0; nf < 2; ++nf) {
            int n = n0 + wn * 32 + nf * 16 + lr;
            float bb1 = b1[e * H_DIM + n], bb2 = b2[e * H_DIM + n];
#pragma unroll
            for (int j = 0; j < 4; ++j) {
                int r = rbase + j;
                if (r < vr) {
                    float x1 = acc1[mf][nf][j] + bb1;
                    float x2 = acc2[mf][nf][j] + bb2;
                    float h = x1 / (1.f + __expf(-x1)) * x2;
                    Hbuf[(size_t)(g0 + r) * H_DIM + n] = f2bf(h);
                }
            }
        }
    }
}

// ---- ffn2: Y = gate * (H@W3 + b3), f32 out ----
// BM=128 BN2=128 BK=64, 512 thr (8 waves 2x4, wave tile 64x32), counted-vmcnt dbuf (4 loads/thread/iter)
__global__ __launch_bounds__(512) void ffn2_kernel(
    const unsigned short* __restrict__ Hbuf, const unsigned short* __restrict__ W3T,
    const float* __restrict__ b3, const float* __restrict__ rowGate,
    float* __restrict__ Ybuf,
    const int* __restrict__ tileE, const int* __restrict__ tileB,
    const int* __restrict__ segOff, const int* __restrict__ counts) {
    int bx = blockIdx.x;
    int e = tileE[bx];
    if (e < 0) return;
    int lb = tileB[bx];
    int g0 = segOff[e] + lb;
    int vr = counts[e] - lb; if (vr > BM) vr = BM;
    int n0 = blockIdx.y * BN2;

    __shared__ __align__(16) unsigned short sA[2][BM * BK];  // 32 KB
    __shared__ __align__(16) unsigned short sB[2][BN2 * BK]; // 32 KB

    int tid = threadIdx.x, lane = tid & 63, w = tid >> 6;
    int wm = w >> 2, wn = w & 3;      // 2 x 4 waves, wave tile 64 x 32
    int lr = lane & 15, lh = lane >> 4;

    f32x4 acc[4][2];
#pragma unroll
    for (int a = 0; a < 4; a++)
#pragma unroll
        for (int b = 0; b < 2; b++) acc[a][b] = (f32x4)0.f;

    const unsigned short* W3e = W3T + (size_t)e * D_IN * H_DIM;

    auto stage = [&](int buf, int kt) {
        int kb = kt * BK;
#pragma unroll
        for (int ca = 0; ca < 2; ca++) {
            int o = ca * 8192 + tid * 16;
            int row = o >> 7;
            int c = ((o >> 4) & 7) ^ (row & 7);
            int gr = g0 + row; if (gr > NP - 1) gr = NP - 1;
            gload_lds16(Hbuf + (size_t)gr * H_DIM + kb + c * 8, (char*)&sA[buf][0] + o);
        }
#pragma unroll
        for (int cb = 0; cb < 2; cb++) {
            int o = cb * 8192 + tid * 16;
            int row = o >> 7;
            int c = ((o >> 4) & 7) ^ (row & 7);
            gload_lds16(W3e + (size_t)(n0 + row) * H_DIM + kb + c * 8, (char*)&sB[buf][0] + o);
        }
    };

    const int NKT = H_DIM / BK; // 48
    stage(0, 0);
    stage(1, 1);
    __builtin_amdgcn_sched_barrier(0);
    for (int kt = 0; kt < NKT; ++kt) {
        if (kt < NKT - 1) { asm volatile("s_waitcnt vmcnt(4)" ::: "memory"); }
        else              { asm volatile("s_waitcnt vmcnt(0)" ::: "memory"); }
        __builtin_amdgcn_s_barrier();
        __builtin_amdgcn_sched_barrier(0);
        int cur = kt & 1;
#pragma unroll
        for (int ks = 0; ks < 2; ++ks) {
            int sb = ks * 4 + lh;
            s16x8 av[4];
#pragma unroll
            for (int mf = 0; mf < 4; ++mf) {
                int r = wm * 64 + mf * 16 + lr;
                av[mf] = *(const s16x8*)&sA[cur][r * 64 + ((sb ^ (r & 7)) << 3)];
            }
#pragma unroll
            for (int nf = 0; nf < 2; ++nf) {
                int n = wn * 32 + nf * 16 + lr;
                s16x8 bv = *(const s16x8*)&sB[cur][n * 64 + ((sb ^ (n & 7)) << 3)];
#pragma unroll
                for (int mf = 0; mf < 4; ++mf)
                    acc[mf][nf] = __builtin_amdgcn_mfma_f32_16x16x32_bf16(av[mf], bv, acc[mf][nf], 0, 0, 0);
            }
        }
        __builtin_amdgcn_sched_barrier(0);
        __builtin_amdgcn_s_barrier();
        if (kt + 2 < NKT) { stage(cur, kt + 2); __builtin_amdgcn_sched_barrier(0); }
    }
#pragma unroll
    for (int mf = 0; mf < 4; ++mf) {
        int rbase = wm * 64 + mf * 16 + lh * 4;
#pragma unroll
        for (int nf = 0; nf < 2; ++nf) {
            int n = n0 + wn * 32 + nf * 16 + lr;
            float bb = b3[e * D_IN + n];
#pragma unroll
            for (int j = 0; j < 4; ++j) {
                int r = rbase + j;
                if (r < vr) {
                    float g = rowGate[g0 + r];
                    Ybuf[(size_t)(g0 + r) * D_IN + n] = g * (acc[mf][nf][j] + bb);
                }
            }
        }
    }
}

// ---- combine: out[t] = Y[p0[t]] + Y[p1[t]] ----
__global__ __launch_bounds__(192) void combine_kernel(
    const float* __restrict__ Ybuf, const int* __restrict__ pairPos, float* __restrict__ out) {
    int t = blockIdx.x, i = threadIdx.x;
    int p0 = pairPos[t * 2], p1 = pairPos[t * 2 + 1];
    float4 a = ((const float4*)(Ybuf + (size_t)p0 * D_IN))[i];
    float4 b = ((const float4*)(Ybuf + (size_t)p1 * D_IN))[i];
    float4 r; r.x = a.x + b.x; r.y = a.y + b.y; r.z = a.z + b.z; r.w = a.w + b.w;
    ((float4*)(out + (size_t)t * D_IN))[i] = r;
}

extern "C" void kernel_launch(void* const* d_in, const int* in_sizes, int n_in,
                              void* d_out, int out_size, void* d_ws, size_t ws_size,
                              hipStream_t stream) {
    const float* x  = (const float*)d_in[0];
    const float* rw = (const float*)d_in[1];
    const float* rb = (const float*)d_in[2];
    const float* w1 = (const float*)d_in[3];
    const float* b1 = (const float*)d_in[4];
    const float* w2 = (const float*)d_in[5];
    const float* b2 = (const float*)d_in[6];
    const float* w3 = (const float*)d_in[7];
    const float* b3 = (const float*)d_in[8];
    float* out = (float*)d_out;

    char* ws = (char*)d_ws;
    const size_t sW = (size_t)N_EXP * H_DIM * D_IN * 2;
    unsigned short* W1T = (unsigned short*)(ws);
    unsigned short* W2T = (unsigned short*)(ws + sW);
    unsigned short* W3T = (unsigned short*)(ws + 2 * sW);
    unsigned short* Xg  = (unsigned short*)(ws + 3 * sW);
    unsigned short* Hb  = (unsigned short*)(ws + 3 * sW + (size_t)NP * D_IN * 2);
    float* Yb = (float*)(ws + 3 * sW + (size_t)NP * D_IN * 2 + (size_t)NP * H_DIM * 2);
    char* meta = (char*)(Yb + (size_t)NP * D_IN);
    int*   counts  = (int*)(meta + 0);
    int*   top1    = (int*)(meta + 32);
    float* psum    = (float*)(meta + 64);
    int*   cursors = (int*)(meta + 96);
    int*   segOff  = (int*)(meta + 128);
    int*   nTiles  = (int*)(meta + 176);
    int*   tileE   = (int*)(meta + 192);
    int*   tileB   = (int*)(meta + 512);
    int*   tk_e    = (int*)(meta + 1024);
    float* tk_w    = (float*)(meta + 1024 + 32768);
    int*   rowTok  = (int*)(meta + 1024 + 65536);
    float* rowGate = (float*)(meta + 1024 + 98304);
    int*   pairPos = (int*)(meta + 1024 + 131072);
    size_t need = (size_t)(meta - ws) + 1024 + 131072 + 32768;
    if (ws_size < need) return;

    hipMemsetAsync(meta, 0, 96, stream);
    dim3 tb(32, 8);
    transpose_cvt_kernel<<<dim3(H_DIM / 32, D_IN / 32, N_EXP), tb, 0, stream>>>(w1, W1T, D_IN, H_DIM);
    transpose_cvt_kernel<<<dim3(H_DIM / 32, D_IN / 32, N_EXP), tb, 0, stream>>>(w2, W2T, D_IN, H_DIM);
    transpose_cvt_kernel<<<dim3(D_IN / 32, H_DIM / 32, N_EXP), tb, 0, stream>>>(w3, W3T, H_DIM, D_IN);
    router_kernel<<<N_TOK / 64, 64, 0, stream>>>(x, rw, rb, counts, top1, psum, tk_e, tk_w);
    scan_kernel<<<1, 64, 0, stream>>>(counts, top1, psum, segOff, cursors, tileE, tileB, nTiles,
                                      out + (size_t)N_TOK * D_IN);
    scatter_kernel<<<N_TOK / 64, 64, 0, stream>>>(tk_e, tk_w, cursors, rowTok, rowGate, pairPos);
    gather_kernel<<<NP, 192, 0, stream>>>(x, rowTok, Xg);
    ffn1_kernel<<<dim3(MAXT, H_DIM / BN1), 256, 0, stream>>>(Xg, W1T, W2T, b1, b2, Hb,
                                                             tileE, tileB, segOff, counts);
    ffn2_kernel<<<dim3(MAXT, D_IN / BN2), 512, 0, stream>>>(Hb, W3T, b3, rowGate, Yb,
                                                            tileE, tileB, segOff, counts);
    combine_kernel<<<N_TOK, 192, 0, stream>>>(Yb, pairPos, out);
}